// Round 2
// baseline (341.530 us; speedup 1.0000x reference)
//
#include <hip/hip_runtime.h>

#define BB 16
#define LL 200
#define HID 128
#define NH 4
#define DH 32
#define IH 96
#define NROW (BB*LL)          // 3200
#define NEGV (-4294967295.0f) // -2^32+1
#define LNEPS 1e-8f

// ---------------- embed: seqs = embed(log_seqs) * sqrt(96), zeroed where id==0
__global__ void k_embed(const int* __restrict__ logs,
                        const int* __restrict__ meta,
                        const float* __restrict__ iW,
                        const float* __restrict__ bW,
                        const float* __restrict__ cW,
                        float* __restrict__ seqs)
{
    int row = blockIdx.x;
    int d = threadIdx.x;
    int id = logs[row];
    float v;
    if (d < IH)            v = iW[(size_t)id*IH + d];
    else if (d < IH + 16)  v = bW[meta[2*id]   *16 + (d-IH)];
    else                   v = cW[meta[2*id+1] *16 + (d-IH-16)];
    v *= 9.797958971132712f;   // sqrt(96)
    if (id == 0) v = 0.f;
    seqs[(size_t)row*HID + d] = v;
}

// ---------------- layernorm over HID=128, 128 threads/row
__global__ void k_ln(const float* __restrict__ in,
                     const float* __restrict__ s,
                     const float* __restrict__ b,
                     float* __restrict__ out)
{
    __shared__ float sh[HID];
    int row = blockIdx.x, d = threadIdx.x;
    float x = in[(size_t)row*HID + d];
    sh[d] = x; __syncthreads();
    for (int off = 64; off; off >>= 1) { if (d < off) sh[d] += sh[d+off]; __syncthreads(); }
    float mu = sh[0] * (1.f/HID);
    __syncthreads();
    float c = x - mu;
    sh[d] = c*c; __syncthreads();
    for (int off = 64; off; off >>= 1) { if (d < off) sh[d] += sh[d+off]; __syncthreads(); }
    float var = sh[0] * (1.f/HID);
    out[(size_t)row*HID + d] = c * rsqrtf(var + LNEPS) * s[d] + b[d];
}

// ---------------- out[row] = in[row] @ W(128x128) + bias  (+relu / +addsrc / *valid)
__global__ void k_mm(const float* __restrict__ in,
                     const float* __restrict__ W,
                     const float* __restrict__ bias,
                     float* __restrict__ out,
                     const float* __restrict__ addsrc,
                     const int* __restrict__ logs,
                     int relu)
{
    __shared__ float rows[2][HID];
    int tid = threadIdx.x;
    int r0 = blockIdx.x * 2;
    int lr = tid >> 7, col = tid & 127;
    rows[lr][col] = in[(size_t)(r0+lr)*HID + col];
    __syncthreads();
    float acc = bias[col];
    const float* rp = rows[lr];
    #pragma unroll 8
    for (int kk = 0; kk < HID; ++kk)
        acc += rp[kk] * W[kk*HID + col];
    if (relu) acc = fmaxf(acc, 0.f);
    int row = r0 + lr;
    if (addsrc) acc += addsrc[(size_t)row*HID + col];
    if (logs && logs[row] == 0) acc = 0.f;
    out[(size_t)row*HID + col] = acc;
}

// ---------------- attention for one (b,i) query row, all 4 heads; writes seqs = Qn + attn_out
__global__ __launch_bounds__(256) void k_attn(
    const float* __restrict__ q, const float* __restrict__ k,
    const float* __restrict__ v, const float* __restrict__ Qn,
    const float* __restrict__ posK, const float* __restrict__ posV,
    const float* __restrict__ timeK, const float* __restrict__ timeV,
    const int* __restrict__ tmat, const int* __restrict__ logs,
    float* __restrict__ seqs_out)
{
    __shared__ float qs[HID];
    __shared__ float sc[NH*LL];
    __shared__ int ts[LL];
    int row = blockIdx.x;
    int b = row / LL, i = row % LL;
    int tid = threadIdx.x;
    if (tid < HID) qs[tid] = q[(size_t)row*HID + tid];
    for (int j = tid; j < LL; j += 256) ts[j] = tmat[(size_t)row*LL + j];
    int valid = (logs[row] != 0);
    __syncthreads();

    // scores: aw[h][j] = q_i . (k_j + posK_j + timeK[t_ij]) / sqrt(32), masked
    for (int e = tid; e < NH*LL; e += 256) {
        int h = e / LL, j = e - h*LL;
        float s;
        if (j > i || !valid) s = NEGV;
        else {
            const float* qp = qs + h*DH;
            const float* kp = k + (size_t)(b*LL + j)*HID + h*DH;
            const float* pp = posK + j*HID + h*DH;
            const float* tp = timeK + ts[j]*HID + h*DH;
            float acc = 0.f;
            #pragma unroll
            for (int d2 = 0; d2 < DH; ++d2)
                acc += qp[d2] * (kp[d2] + pp[d2] + tp[d2]);
            s = acc * 0.17677669529663687f; // 1/sqrt(32)
        }
        sc[e] = s;
    }
    __syncthreads();

    // softmax over j per head: wave w handles head w (64 lanes)
    {
        int h = tid >> 6, lane = tid & 63;
        float m = -INFINITY;
        for (int j = lane; j < LL; j += 64) m = fmaxf(m, sc[h*LL + j]);
        for (int off = 32; off; off >>= 1) m = fmaxf(m, __shfl_xor(m, off));
        float ssum = 0.f;
        for (int j = lane; j < LL; j += 64) {
            float e = expf(sc[h*LL + j] - m);
            sc[h*LL + j] = e; ssum += e;
        }
        for (int off = 32; off; off >>= 1) ssum += __shfl_xor(ssum, off);
        float inv = 1.f / ssum;
        for (int j = lane; j < LL; j += 64) sc[h*LL + j] *= inv;
    }
    __syncthreads();

    // out[h][dd] = sum_j A[h][j] * (v_j + posV_j + timeV[t_ij]); residual from Qn
    if (tid < HID) {
        int h = tid >> 5;
        int jmax = valid ? i : (LL - 1);   // valid rows: A==0 for j>i exactly (exp underflow)
        float acc = 0.f;
        for (int j = 0; j <= jmax; ++j) {
            float a = sc[h*LL + j];
            acc += a * ( v[(size_t)(b*LL + j)*HID + tid]
                       + posV[j*HID + tid]
                       + timeV[ts[j]*HID + tid] );
        }
        seqs_out[(size_t)row*HID + tid] = Qn[(size_t)row*HID + tid] + acc;
    }
}

// ---------------- last LN + pos/neg logits
__global__ void k_logits(const float* __restrict__ seqs,
                         const float* __restrict__ ls, const float* __restrict__ lb,
                         const int* __restrict__ pos, const int* __restrict__ neg,
                         const int* __restrict__ meta,
                         const float* __restrict__ iW, const float* __restrict__ bW,
                         const float* __restrict__ cW,
                         float* __restrict__ out)
{
    __shared__ float sh[HID];
    int row = blockIdx.x, d = threadIdx.x;
    float x = seqs[(size_t)row*HID + d];
    sh[d] = x; __syncthreads();
    for (int off = 64; off; off >>= 1) { if (d < off) sh[d] += sh[d+off]; __syncthreads(); }
    float mu = sh[0] * (1.f/HID);
    __syncthreads();
    float c = x - mu;
    sh[d] = c*c; __syncthreads();
    for (int off = 64; off; off >>= 1) { if (d < off) sh[d] += sh[d+off]; __syncthreads(); }
    float f = c * rsqrtf(sh[0]*(1.f/HID) + LNEPS) * ls[d] + lb[d];
    __syncthreads();

    // pos logit
    int pid = pos[row];
    float e;
    if (d < IH)           e = iW[(size_t)pid*IH + d];
    else if (d < IH + 16) e = bW[meta[2*pid]   *16 + (d-IH)];
    else                  e = cW[meta[2*pid+1] *16 + (d-IH-16)];
    sh[d] = f * e; __syncthreads();
    for (int off = 64; off; off >>= 1) { if (d < off) sh[d] += sh[d+off]; __syncthreads(); }
    if (d == 0) out[row] = sh[0];
    __syncthreads();

    // neg logit
    int nid = neg[row];
    if (d < IH)           e = iW[(size_t)nid*IH + d];
    else if (d < IH + 16) e = bW[meta[2*nid]   *16 + (d-IH)];
    else                  e = cW[meta[2*nid+1] *16 + (d-IH-16)];
    sh[d] = f * e; __syncthreads();
    for (int off = 64; off; off >>= 1) { if (d < off) sh[d] += sh[d+off]; __syncthreads(); }
    if (d == 0) out[NROW + row] = sh[0];
}

extern "C" void kernel_launch(void* const* d_in, const int* in_sizes, int n_in,
                              void* d_out, int out_size, void* d_ws, size_t ws_size,
                              hipStream_t stream)
{
    const int*  logs = (const int*)d_in[1];
    const int*  tmat = (const int*)d_in[2];
    const int*  pos  = (const int*)d_in[3];
    const int*  neg  = (const int*)d_in[4];
    const int*  meta = (const int*)d_in[5];
    const float* iW   = (const float*)d_in[6];
    const float* bW   = (const float*)d_in[7];
    const float* cW   = (const float*)d_in[8];
    const float* posK = (const float*)d_in[9];
    const float* posV = (const float*)d_in[10];
    const float* tK   = (const float*)d_in[11];
    const float* tV   = (const float*)d_in[12];
    const float* attn_s = (const float*)d_in[13];
    const float* attn_b = (const float*)d_in[14];
    const float* Qw = (const float*)d_in[15];
    const float* Qb = (const float*)d_in[16];
    const float* Kw = (const float*)d_in[17];
    const float* Kb = (const float*)d_in[18];
    const float* Vw = (const float*)d_in[19];
    const float* Vb = (const float*)d_in[20];
    const float* fwd_s = (const float*)d_in[21];
    const float* fwd_b = (const float*)d_in[22];
    const float* c1w = (const float*)d_in[23];
    const float* c1b = (const float*)d_in[24];
    const float* c2w = (const float*)d_in[25];
    const float* c2b = (const float*)d_in[26];
    const float* lls = (const float*)d_in[27];
    const float* llb = (const float*)d_in[28];

    const size_t RC = (size_t)NROW * HID;
    float* seqs = (float*)d_ws;
    float* Qn   = seqs + RC;
    float* qbuf = Qn   + RC;
    float* kbuf = qbuf + RC;
    float* vbuf = kbuf + RC;
    float* X    = vbuf + RC;   // also reuses nothing; 7 buffers = 11.5 MB total
    float* H1   = X    + RC;

    k_embed<<<NROW, 128, 0, stream>>>(logs, meta, iW, bW, cW, seqs);

    for (int i = 0; i < 2; ++i) {
        size_t wo = (size_t)i * HID * HID;
        size_t bo = (size_t)i * HID;
        k_ln<<<NROW, 128, 0, stream>>>(seqs, attn_s + bo, attn_b + bo, Qn);
        k_mm<<<NROW/2, 256, 0, stream>>>(Qn,   Qw + wo, Qb + bo, qbuf, nullptr, nullptr, 0);
        k_mm<<<NROW/2, 256, 0, stream>>>(seqs, Kw + wo, Kb + bo, kbuf, nullptr, nullptr, 0);
        k_mm<<<NROW/2, 256, 0, stream>>>(seqs, Vw + wo, Vb + bo, vbuf, nullptr, nullptr, 0);
        k_attn<<<NROW, 256, 0, stream>>>(qbuf, kbuf, vbuf, Qn, posK, posV, tK, tV, tmat, logs, seqs);
        k_ln<<<NROW, 128, 0, stream>>>(seqs, fwd_s + bo, fwd_b + bo, X);
        k_mm<<<NROW/2, 256, 0, stream>>>(X,  c1w + wo, c1b + bo, H1,   nullptr, nullptr, 1);
        k_mm<<<NROW/2, 256, 0, stream>>>(H1, c2w + wo, c2b + bo, seqs, X,       logs,    0);
    }

    k_logits<<<NROW, 128, 0, stream>>>(seqs, lls, llb, pos, neg, meta, iW, bW, cW, (float*)d_out);
}

// Round 3
// 230.468 us; speedup vs baseline: 1.4819x; 1.4819x over previous
//
#include <hip/hip_runtime.h>

#define BB 16
#define LL 200
#define HID 128
#define NH 4
#define DH 32
#define IH 96
#define NROW (BB*LL)          // 3200
#define LNEPS 1e-8f

// ---------------- embed: seqs = embed(log_seqs) * sqrt(96), zeroed where id==0
__global__ void k_embed(const int* __restrict__ logs,
                        const int* __restrict__ meta,
                        const float* __restrict__ iW,
                        const float* __restrict__ bW,
                        const float* __restrict__ cW,
                        float* __restrict__ seqs)
{
    int row = blockIdx.x;
    int d = threadIdx.x;
    int id = logs[row];
    float v;
    if (d < IH)            v = iW[(size_t)id*IH + d];
    else if (d < IH + 16)  v = bW[meta[2*id]   *16 + (d-IH)];
    else                   v = cW[meta[2*id+1] *16 + (d-IH-16)];
    v *= 9.797958971132712f;   // sqrt(96)
    if (id == 0) v = 0.f;
    seqs[(size_t)row*HID + d] = v;
}

// ---------------- fused attn-LN + Q/K/V GEMMs; folds posK into kbuf, posV into vbuf
__global__ __launch_bounds__(256) void k_lnqkv(
    const float* __restrict__ seqs,
    const float* __restrict__ lns, const float* __restrict__ lnb,
    const float* __restrict__ Qw, const float* __restrict__ Qb,
    const float* __restrict__ Kw, const float* __restrict__ Kb,
    const float* __restrict__ Vw, const float* __restrict__ Vb,
    const float* __restrict__ posK, const float* __restrict__ posV,
    float* __restrict__ Qn, float* __restrict__ qbuf,
    float* __restrict__ kbuf, float* __restrict__ vbuf)
{
    __shared__ float xs[2][HID];
    __shared__ float qn[2][HID];
    __shared__ float rs[2][HID];
    int tid = threadIdx.x, lr = tid >> 7, col = tid & 127;
    int row = blockIdx.x * 2 + lr;
    float x = seqs[row*HID + col];
    xs[lr][col] = x;
    rs[lr][col] = x;
    __syncthreads();
    for (int off = 64; off; off >>= 1) { if (col < off) rs[lr][col] += rs[lr][col+off]; __syncthreads(); }
    float mu = rs[lr][0] * (1.f/HID);
    __syncthreads();
    float c = x - mu;
    rs[lr][col] = c*c; __syncthreads();
    for (int off = 64; off; off >>= 1) { if (col < off) rs[lr][col] += rs[lr][col+off]; __syncthreads(); }
    float ln = c * rsqrtf(rs[lr][0]*(1.f/HID) + LNEPS) * lns[col] + lnb[col];
    qn[lr][col] = ln;
    Qn[row*HID + col] = ln;
    __syncthreads();

    int l = row - (row / LL) * LL;   // position in sequence
    float qa = Qb[col];
    float ka = Kb[col] + posK[l*HID + col];
    float va = Vb[col] + posV[l*HID + col];
    const float* qrow = qn[lr];
    const float* xrow = xs[lr];
    #pragma unroll 4
    for (int kk = 0; kk < HID; ++kk) {
        float xq = qrow[kk], xv = xrow[kk];
        qa += xq * Qw[kk*HID + col];
        ka += xv * Kw[kk*HID + col];
        va += xv * Vw[kk*HID + col];
    }
    qbuf[row*HID + col] = qa;
    kbuf[row*HID + col] = ka;
    vbuf[row*HID + col] = va;
}

// ---------------- attention: one (b,i) query row per block, float4 everywhere
__global__ __launch_bounds__(256) void k_attn(
    const float4* __restrict__ q4,   // [NROW][32]
    const float4* __restrict__ kp4,  // k + posK
    const float4* __restrict__ vp4,  // v + posV
    const float4* __restrict__ Qn4,
    const float4* __restrict__ tK4,  // [257][32]
    const float4* __restrict__ tV4,
    const int* __restrict__ tmat, const int* __restrict__ logs,
    float4* __restrict__ seqs_out4)
{
    __shared__ float4 qs4[32];
    __shared__ float sc[NH*LL];
    __shared__ int ts[LL];
    __shared__ float4 red4[8*32];
    int row = blockIdx.x;
    int b = row / LL, i = row - b*LL;
    int tid = threadIdx.x;
    if (tid < 32) qs4[tid] = q4[(size_t)row*32 + tid];
    for (int j = tid; j < LL; j += 256) ts[j] = tmat[(size_t)row*LL + j];
    int valid = (logs[row] != 0);
    __syncthreads();

    int nj = valid ? (i + 1) : LL;

    // scores for j <= i only: sc[h][j] = q_h . (kp_j + tK[ts_j]) / sqrt(32)
    if (valid) {
        int tot = 4*nj;
        for (int e = tid; e < tot; e += 256) {
            int h = e & 3, j = e >> 2;
            const float4* kr = kp4 + ((size_t)(b*LL + j))*32 + h*8;
            const float4* tr = tK4 + ((size_t)ts[j])*32 + h*8;
            const float4* qr = qs4 + h*8;
            float acc = 0.f;
            #pragma unroll
            for (int r = 0; r < 8; ++r) {
                float4 a = qr[r], x = kr[r], y = tr[r];
                acc += a.x*(x.x+y.x) + a.y*(x.y+y.y) + a.z*(x.z+y.z) + a.w*(x.w+y.w);
            }
            sc[h*LL + j] = acc * 0.17677669529663687f; // 1/sqrt(32)
        }
    } else {
        for (int e = tid; e < NH*LL; e += 256) sc[e] = 0.f; // -> uniform softmax
    }
    __syncthreads();

    // softmax per head over j < nj (wave per head)
    {
        int h = tid >> 6, lane = tid & 63;
        float m = -INFINITY;
        for (int j = lane; j < nj; j += 64) m = fmaxf(m, sc[h*LL + j]);
        for (int off = 32; off; off >>= 1) m = fmaxf(m, __shfl_xor(m, off));
        float s = 0.f;
        for (int j = lane; j < nj; j += 64) {
            float e = expf(sc[h*LL + j] - m);
            sc[h*LL + j] = e; s += e;
        }
        for (int off = 32; off; off >>= 1) s += __shfl_xor(s, off);
        float inv = 1.f / s;
        for (int j = lane; j < nj; j += 64) sc[h*LL + j] *= inv;
    }
    __syncthreads();

    // PV: 8-way j-split x 32 float4 d-columns, all 256 threads
    {
        int d4 = tid & 31, jc = tid >> 5;
        int h = d4 >> 3;
        float4 acc = {0.f, 0.f, 0.f, 0.f};
        for (int j = jc; j < nj; j += 8) {
            float a = sc[h*LL + j];
            float4 x = vp4[((size_t)(b*LL + j))*32 + d4];
            float4 y = tV4[((size_t)ts[j])*32 + d4];
            acc.x += a*(x.x+y.x); acc.y += a*(x.y+y.y);
            acc.z += a*(x.z+y.z); acc.w += a*(x.w+y.w);
        }
        red4[jc*32 + d4] = acc;
    }
    __syncthreads();
    if (tid < 32) {
        float4 t = red4[tid];
        #pragma unroll
        for (int jc = 1; jc < 8; ++jc) {
            float4 r = red4[jc*32 + tid];
            t.x += r.x; t.y += r.y; t.z += r.z; t.w += r.w;
        }
        float4 qn = Qn4[(size_t)row*32 + tid];
        t.x += qn.x; t.y += qn.y; t.z += qn.z; t.w += qn.w;
        seqs_out4[(size_t)row*32 + tid] = t;
    }
}

// ---------------- fused fwd-LN + FFN (c1 relu, c2) + residual + valid mask
__global__ __launch_bounds__(256) void k_ffn(
    const float* __restrict__ seqs_in,
    const float* __restrict__ lns, const float* __restrict__ lnb,
    const float* __restrict__ c1w, const float* __restrict__ c1b,
    const float* __restrict__ c2w, const float* __restrict__ c2b,
    const int* __restrict__ logs,
    float* __restrict__ seqs_out)
{
    __shared__ float xsh[2][HID];
    __shared__ float h1[2][HID];
    __shared__ float rs[2][HID];
    int tid = threadIdx.x, lr = tid >> 7, col = tid & 127;
    int row = blockIdx.x * 2 + lr;
    float x = seqs_in[row*HID + col];
    rs[lr][col] = x;
    __syncthreads();
    for (int off = 64; off; off >>= 1) { if (col < off) rs[lr][col] += rs[lr][col+off]; __syncthreads(); }
    float mu = rs[lr][0] * (1.f/HID);
    __syncthreads();
    float c = x - mu;
    rs[lr][col] = c*c; __syncthreads();
    for (int off = 64; off; off >>= 1) { if (col < off) rs[lr][col] += rs[lr][col+off]; __syncthreads(); }
    float X = c * rsqrtf(rs[lr][0]*(1.f/HID) + LNEPS) * lns[col] + lnb[col];
    xsh[lr][col] = X;
    __syncthreads();

    float a1 = c1b[col];
    const float* xr = xsh[lr];
    #pragma unroll 4
    for (int kk = 0; kk < HID; ++kk) a1 += xr[kk] * c1w[kk*HID + col];
    h1[lr][col] = fmaxf(a1, 0.f);
    __syncthreads();

    float a2 = c2b[col];
    const float* hr = h1[lr];
    #pragma unroll 4
    for (int kk = 0; kk < HID; ++kk) a2 += hr[kk] * c2w[kk*HID + col];
    float o = X + a2;
    if (logs[row] == 0) o = 0.f;
    seqs_out[row*HID + col] = o;
}

// ---------------- last LN + pos/neg logits
__global__ void k_logits(const float* __restrict__ seqs,
                         const float* __restrict__ ls, const float* __restrict__ lb,
                         const int* __restrict__ pos, const int* __restrict__ neg,
                         const int* __restrict__ meta,
                         const float* __restrict__ iW, const float* __restrict__ bW,
                         const float* __restrict__ cW,
                         float* __restrict__ out)
{
    __shared__ float sh[HID];
    int row = blockIdx.x, d = threadIdx.x;
    float x = seqs[(size_t)row*HID + d];
    sh[d] = x; __syncthreads();
    for (int off = 64; off; off >>= 1) { if (d < off) sh[d] += sh[d+off]; __syncthreads(); }
    float mu = sh[0] * (1.f/HID);
    __syncthreads();
    float c = x - mu;
    sh[d] = c*c; __syncthreads();
    for (int off = 64; off; off >>= 1) { if (d < off) sh[d] += sh[d+off]; __syncthreads(); }
    float f = c * rsqrtf(sh[0]*(1.f/HID) + LNEPS) * ls[d] + lb[d];
    __syncthreads();

    int pid = pos[row];
    float e;
    if (d < IH)           e = iW[(size_t)pid*IH + d];
    else if (d < IH + 16) e = bW[meta[2*pid]   *16 + (d-IH)];
    else                  e = cW[meta[2*pid+1] *16 + (d-IH-16)];
    sh[d] = f * e; __syncthreads();
    for (int off = 64; off; off >>= 1) { if (d < off) sh[d] += sh[d+off]; __syncthreads(); }
    if (d == 0) out[row] = sh[0];
    __syncthreads();

    int nid = neg[row];
    if (d < IH)           e = iW[(size_t)nid*IH + d];
    else if (d < IH + 16) e = bW[meta[2*nid]   *16 + (d-IH)];
    else                  e = cW[meta[2*nid+1] *16 + (d-IH-16)];
    sh[d] = f * e; __syncthreads();
    for (int off = 64; off; off >>= 1) { if (d < off) sh[d] += sh[d+off]; __syncthreads(); }
    if (d == 0) out[NROW + row] = sh[0];
}

extern "C" void kernel_launch(void* const* d_in, const int* in_sizes, int n_in,
                              void* d_out, int out_size, void* d_ws, size_t ws_size,
                              hipStream_t stream)
{
    const int*  logs = (const int*)d_in[1];
    const int*  tmat = (const int*)d_in[2];
    const int*  pos  = (const int*)d_in[3];
    const int*  neg  = (const int*)d_in[4];
    const int*  meta = (const int*)d_in[5];
    const float* iW   = (const float*)d_in[6];
    const float* bW   = (const float*)d_in[7];
    const float* cW   = (const float*)d_in[8];
    const float* posK = (const float*)d_in[9];
    const float* posV = (const float*)d_in[10];
    const float* tK   = (const float*)d_in[11];
    const float* tV   = (const float*)d_in[12];
    const float* attn_s = (const float*)d_in[13];
    const float* attn_b = (const float*)d_in[14];
    const float* Qw = (const float*)d_in[15];
    const float* Qb = (const float*)d_in[16];
    const float* Kw = (const float*)d_in[17];
    const float* Kb = (const float*)d_in[18];
    const float* Vw = (const float*)d_in[19];
    const float* Vb = (const float*)d_in[20];
    const float* fwd_s = (const float*)d_in[21];
    const float* fwd_b = (const float*)d_in[22];
    const float* c1w = (const float*)d_in[23];
    const float* c1b = (const float*)d_in[24];
    const float* c2w = (const float*)d_in[25];
    const float* c2b = (const float*)d_in[26];
    const float* lls = (const float*)d_in[27];
    const float* llb = (const float*)d_in[28];

    const size_t RC = (size_t)NROW * HID;
    float* seqs = (float*)d_ws;
    float* Qn   = seqs + RC;
    float* qbuf = Qn   + RC;
    float* kbuf = qbuf + RC;
    float* vbuf = kbuf + RC;

    k_embed<<<NROW, 128, 0, stream>>>(logs, meta, iW, bW, cW, seqs);

    for (int i = 0; i < 2; ++i) {
        size_t wo = (size_t)i * HID * HID;
        size_t bo = (size_t)i * HID;
        k_lnqkv<<<NROW/2, 256, 0, stream>>>(seqs, attn_s + bo, attn_b + bo,
                                            Qw + wo, Qb + bo, Kw + wo, Kb + bo,
                                            Vw + wo, Vb + bo, posK, posV,
                                            Qn, qbuf, kbuf, vbuf);
        k_attn<<<NROW, 256, 0, stream>>>((const float4*)qbuf, (const float4*)kbuf,
                                         (const float4*)vbuf, (const float4*)Qn,
                                         (const float4*)tK, (const float4*)tV,
                                         tmat, logs, (float4*)seqs);
        k_ffn<<<NROW/2, 256, 0, stream>>>(seqs, fwd_s + bo, fwd_b + bo,
                                          c1w + wo, c1b + bo, c2w + wo, c2b + bo,
                                          logs, seqs);
    }

    k_logits<<<NROW, 128, 0, stream>>>(seqs, lls, llb, pos, neg, meta, iW, bW, cW, (float*)d_out);
}

// Round 4
// 198.144 us; speedup vs baseline: 1.7236x; 1.1631x over previous
//
#include <hip/hip_runtime.h>

#define BB 16
#define LL 200
#define HID 128
#define NH 4
#define DH 32
#define IH 96
#define NROW (BB*LL)          // 3200
#define LNEPS 1e-8f

// ---------------- embed: seqs = embed(log_seqs) * sqrt(96), zeroed where id==0
__global__ void k_embed(const int* __restrict__ logs,
                        const int* __restrict__ meta,
                        const float* __restrict__ iW,
                        const float* __restrict__ bW,
                        const float* __restrict__ cW,
                        float* __restrict__ seqs)
{
    int row = blockIdx.x;
    int d = threadIdx.x;
    int id = logs[row];
    float v;
    if (d < IH)            v = iW[(size_t)id*IH + d];
    else if (d < IH + 16)  v = bW[meta[2*id]   *16 + (d-IH)];
    else                   v = cW[meta[2*id+1] *16 + (d-IH-16)];
    v *= 9.797958971132712f;   // sqrt(96)
    if (id == 0) v = 0.f;
    seqs[(size_t)row*HID + d] = v;
}

// ---------------- fused attn-LN + Q/K/V GEMVs, 8 rows/block (weights amortized 4x)
__global__ __launch_bounds__(512) void k_lnqkv(
    const float* __restrict__ seqs,
    const float* __restrict__ lns, const float* __restrict__ lnb,
    const float* __restrict__ Qw, const float* __restrict__ Qb,
    const float* __restrict__ Kw, const float* __restrict__ Kb,
    const float* __restrict__ Vw, const float* __restrict__ Vb,
    const float* __restrict__ posK, const float* __restrict__ posV,
    float* __restrict__ Qn, float* __restrict__ qbuf,
    float* __restrict__ kbuf, float* __restrict__ vbuf)
{
    __shared__ float xs[8][HID];
    __shared__ float qn[8][HID];
    __shared__ float red[4][HID];
    int tid = threadIdx.x;
    int g = tid >> 7, col = tid & 127;
    int r0 = blockIdx.x * 8;

    #pragma unroll
    for (int p = 0; p < 2; ++p) {
        int rr = g + p*4;
        int row = r0 + rr;
        float x = seqs[(size_t)row*HID + col];
        xs[rr][col] = x;
        red[g][col] = x;
        __syncthreads();
        for (int off = 64; off; off >>= 1) { if (col < off) red[g][col] += red[g][col+off]; __syncthreads(); }
        float mu = red[g][0] * (1.f/HID);
        __syncthreads();
        float c = x - mu;
        red[g][col] = c*c; __syncthreads();
        for (int off = 64; off; off >>= 1) { if (col < off) red[g][col] += red[g][col+off]; __syncthreads(); }
        float ln = c * rsqrtf(red[g][0]*(1.f/HID) + LNEPS) * lns[col] + lnb[col];
        qn[rr][col] = ln;
        Qn[(size_t)row*HID + col] = ln;
        __syncthreads();
    }

    // GEMV: thread (col, rg) computes rows 2rg, 2rg+1 for Q,K,V
    int rg = g;
    int rA = 2*rg, rB = 2*rg + 1;
    float aq0 = Qb[col], aq1 = aq0;
    float ak0 = Kb[col], ak1 = ak0;
    float av0 = Vb[col], av1 = av0;
    const float* q0 = qn[rA]; const float* q1 = qn[rB];
    const float* x0 = xs[rA]; const float* x1 = xs[rB];
    #pragma unroll 4
    for (int kk = 0; kk < HID; ++kk) {
        float wq = Qw[kk*HID + col];
        float wk = Kw[kk*HID + col];
        float wv = Vw[kk*HID + col];
        aq0 += q0[kk]*wq; aq1 += q1[kk]*wq;
        ak0 += x0[kk]*wk; ak1 += x1[kk]*wk;
        av0 += x0[kk]*wv; av1 += x1[kk]*wv;
    }
    int rowA = r0 + rA, rowB = r0 + rB;
    int lA = rowA % LL, lB = rowB % LL;
    qbuf[(size_t)rowA*HID + col] = aq0;
    qbuf[(size_t)rowB*HID + col] = aq1;
    kbuf[(size_t)rowA*HID + col] = ak0 + posK[lA*HID + col];
    kbuf[(size_t)rowB*HID + col] = ak1 + posK[lB*HID + col];
    vbuf[(size_t)rowA*HID + col] = av0 + posV[lA*HID + col];
    vbuf[(size_t)rowB*HID + col] = av1 + posV[lB*HID + col];
}

// ---------------- attention: one wave per (row, head); zero LDS, zero barriers
__global__ __launch_bounds__(64) void k_attn(
    const float*  __restrict__ q,    // qbuf  [NROW][128]
    const float4* __restrict__ kp4,  // k + posK, [NROW][32]
    const float4* __restrict__ vp4,  // v + posV
    const float4* __restrict__ Qn4,
    const float4* __restrict__ tK4,  // [257][32]
    const float4* __restrict__ tV4,
    const int* __restrict__ tmat, const int* __restrict__ logs,
    float4* __restrict__ out4)
{
    int blk = blockIdx.x;
    int h  = blk & 3;
    int r2 = blk >> 2;
    int i  = 199 - (r2 >> 4);        // biggest rows dispatched first
    int b  = r2 & 15;
    int row = b*LL + i;
    int lane = threadIdx.x;
    int valid = (logs[row] != 0);
    int nj = valid ? (i + 1) : LL;

    // q slice for this head: wave-uniform addresses -> scalar loads
    const float* qp = q + (size_t)row*HID + h*DH;
    float qv[32];
    #pragma unroll
    for (int t = 0; t < 32; ++t) qv[t] = qp[t];

    // scores: 4 chunks of 64 j's, everything in registers
    float ev[4]; int tsv[4];
    #pragma unroll
    for (int c = 0; c < 4; ++c) {
        int j = c*64 + lane;
        tsv[c] = 0;
        float s = -INFINITY;
        if (j < nj) {
            tsv[c] = tmat[(size_t)row*LL + j];
            if (valid) {
                const float4* kr = kp4 + ((size_t)(b*LL + j))*32 + h*8;
                const float4* tr = tK4 + ((size_t)tsv[c])*32 + h*8;
                float acc = 0.f;
                #pragma unroll
                for (int r = 0; r < 8; ++r) {
                    float4 kx = kr[r], tx = tr[r];
                    acc += qv[4*r+0]*(kx.x+tx.x) + qv[4*r+1]*(kx.y+tx.y)
                         + qv[4*r+2]*(kx.z+tx.z) + qv[4*r+3]*(kx.w+tx.w);
                }
                s = acc * 0.17677669529663687f; // 1/sqrt(32)
            } else {
                s = 0.f;                         // invalid row -> uniform softmax
            }
        }
        ev[c] = s;
    }

    // softmax (in-register, wave-level)
    float m = fmaxf(fmaxf(ev[0], ev[1]), fmaxf(ev[2], ev[3]));
    #pragma unroll
    for (int off = 32; off; off >>= 1) m = fmaxf(m, __shfl_xor(m, off));
    float ssum = 0.f;
    #pragma unroll
    for (int c = 0; c < 4; ++c) {
        int j = c*64 + lane;
        float e = (j < nj) ? __expf(ev[c] - m) : 0.f;
        ev[c] = e; ssum += e;
    }
    #pragma unroll
    for (int off = 32; off; off >>= 1) ssum += __shfl_xor(ssum, off);
    float inv = 1.f / ssum;

    // PV: lanes = (jc in 0..7) x (d4 in 0..7); coalesced 128B per j-row
    int jc = lane >> 3, d4 = lane & 7;
    float4 acc = {0.f, 0.f, 0.f, 0.f};
    #pragma unroll
    for (int c = 0; c < 4; ++c) {
        int jlo = c*64;
        int jhi = (jlo + 64 < nj) ? (jlo + 64) : nj;
        for (int jj = jlo; jj < jhi; jj += 8) {
            int j = jj + jc;
            float a  = __shfl(ev[c],  j & 63);
            int  tsj = __shfl(tsv[c], j & 63);
            if (j < jhi) {
                float4 vx = vp4[((size_t)(b*LL + j))*32 + h*8 + d4];
                float4 tx = tV4[((size_t)tsj)*32 + h*8 + d4];
                acc.x += a*(vx.x+tx.x); acc.y += a*(vx.y+tx.y);
                acc.z += a*(vx.z+tx.z); acc.w += a*(vx.w+tx.w);
            }
        }
    }
    // reduce over the 8 jc groups
    #pragma unroll
    for (int off = 8; off < 64; off <<= 1) {
        acc.x += __shfl_xor(acc.x, off);
        acc.y += __shfl_xor(acc.y, off);
        acc.z += __shfl_xor(acc.z, off);
        acc.w += __shfl_xor(acc.w, off);
    }
    if (jc == 0) {
        float4 qn = Qn4[(size_t)row*32 + h*8 + d4];
        float4 o;
        o.x = qn.x + acc.x*inv;
        o.y = qn.y + acc.y*inv;
        o.z = qn.z + acc.z*inv;
        o.w = qn.w + acc.w*inv;
        out4[(size_t)row*32 + h*8 + d4] = o;
    }
}

// ---------------- fused fwd-LN + FFN + residual + valid mask, 8 rows/block
__global__ __launch_bounds__(512) void k_ffn(
    const float* __restrict__ seqs_in,
    const float* __restrict__ lns, const float* __restrict__ lnb,
    const float* __restrict__ c1w, const float* __restrict__ c1b,
    const float* __restrict__ c2w, const float* __restrict__ c2b,
    const int* __restrict__ logs,
    float* __restrict__ seqs_out)
{
    __shared__ float xs[8][HID];
    __shared__ float h1[8][HID];
    __shared__ float red[4][HID];
    int tid = threadIdx.x;
    int g = tid >> 7, col = tid & 127;
    int r0 = blockIdx.x * 8;

    #pragma unroll
    for (int p = 0; p < 2; ++p) {
        int rr = g + p*4;
        int row = r0 + rr;
        float x = seqs_in[(size_t)row*HID + col];
        red[g][col] = x;
        __syncthreads();
        for (int off = 64; off; off >>= 1) { if (col < off) red[g][col] += red[g][col+off]; __syncthreads(); }
        float mu = red[g][0] * (1.f/HID);
        __syncthreads();
        float c = x - mu;
        red[g][col] = c*c; __syncthreads();
        for (int off = 64; off; off >>= 1) { if (col < off) red[g][col] += red[g][col+off]; __syncthreads(); }
        xs[rr][col] = c * rsqrtf(red[g][0]*(1.f/HID) + LNEPS) * lns[col] + lnb[col];
        __syncthreads();
    }

    // GEMV1 + relu
    int rg = g;
    int rA = 2*rg, rB = 2*rg + 1;
    {
        float a0 = c1b[col], a1 = a0;
        const float* x0 = xs[rA]; const float* x1 = xs[rB];
        #pragma unroll 4
        for (int kk = 0; kk < HID; ++kk) {
            float w = c1w[kk*HID + col];
            a0 += x0[kk]*w; a1 += x1[kk]*w;
        }
        h1[rA][col] = fmaxf(a0, 0.f);
        h1[rB][col] = fmaxf(a1, 0.f);
    }
    __syncthreads();

    // GEMV2 + residual + mask
    {
        float a0 = c2b[col], a1 = a0;
        const float* y0 = h1[rA]; const float* y1 = h1[rB];
        #pragma unroll 4
        for (int kk = 0; kk < HID; ++kk) {
            float w = c2w[kk*HID + col];
            a0 += y0[kk]*w; a1 += y1[kk]*w;
        }
        int rowA = r0 + rA, rowB = r0 + rB;
        float o0 = xs[rA][col] + a0;
        float o1 = xs[rB][col] + a1;
        if (logs[rowA] == 0) o0 = 0.f;
        if (logs[rowB] == 0) o1 = 0.f;
        seqs_out[(size_t)rowA*HID + col] = o0;
        seqs_out[(size_t)rowB*HID + col] = o1;
    }
}

// ---------------- last LN + pos/neg logits
__global__ void k_logits(const float* __restrict__ seqs,
                         const float* __restrict__ ls, const float* __restrict__ lb,
                         const int* __restrict__ pos, const int* __restrict__ neg,
                         const int* __restrict__ meta,
                         const float* __restrict__ iW, const float* __restrict__ bW,
                         const float* __restrict__ cW,
                         float* __restrict__ out)
{
    __shared__ float sh[HID];
    int row = blockIdx.x, d = threadIdx.x;
    float x = seqs[(size_t)row*HID + d];
    sh[d] = x; __syncthreads();
    for (int off = 64; off; off >>= 1) { if (d < off) sh[d] += sh[d+off]; __syncthreads(); }
    float mu = sh[0] * (1.f/HID);
    __syncthreads();
    float c = x - mu;
    sh[d] = c*c; __syncthreads();
    for (int off = 64; off; off >>= 1) { if (d < off) sh[d] += sh[d+off]; __syncthreads(); }
    float f = c * rsqrtf(sh[0]*(1.f/HID) + LNEPS) * ls[d] + lb[d];
    __syncthreads();

    int pid = pos[row];
    float e;
    if (d < IH)           e = iW[(size_t)pid*IH + d];
    else if (d < IH + 16) e = bW[meta[2*pid]   *16 + (d-IH)];
    else                  e = cW[meta[2*pid+1] *16 + (d-IH-16)];
    sh[d] = f * e; __syncthreads();
    for (int off = 64; off; off >>= 1) { if (d < off) sh[d] += sh[d+off]; __syncthreads(); }
    if (d == 0) out[row] = sh[0];
    __syncthreads();

    int nid = neg[row];
    if (d < IH)           e = iW[(size_t)nid*IH + d];
    else if (d < IH + 16) e = bW[meta[2*nid]   *16 + (d-IH)];
    else                  e = cW[meta[2*nid+1] *16 + (d-IH-16)];
    sh[d] = f * e; __syncthreads();
    for (int off = 64; off; off >>= 1) { if (d < off) sh[d] += sh[d+off]; __syncthreads(); }
    if (d == 0) out[NROW + row] = sh[0];
}

extern "C" void kernel_launch(void* const* d_in, const int* in_sizes, int n_in,
                              void* d_out, int out_size, void* d_ws, size_t ws_size,
                              hipStream_t stream)
{
    const int*  logs = (const int*)d_in[1];
    const int*  tmat = (const int*)d_in[2];
    const int*  pos  = (const int*)d_in[3];
    const int*  neg  = (const int*)d_in[4];
    const int*  meta = (const int*)d_in[5];
    const float* iW   = (const float*)d_in[6];
    const float* bW   = (const float*)d_in[7];
    const float* cW   = (const float*)d_in[8];
    const float* posK = (const float*)d_in[9];
    const float* posV = (const float*)d_in[10];
    const float* tK   = (const float*)d_in[11];
    const float* tV   = (const float*)d_in[12];
    const float* attn_s = (const float*)d_in[13];
    const float* attn_b = (const float*)d_in[14];
    const float* Qw = (const float*)d_in[15];
    const float* Qb = (const float*)d_in[16];
    const float* Kw = (const float*)d_in[17];
    const float* Kb = (const float*)d_in[18];
    const float* Vw = (const float*)d_in[19];
    const float* Vb = (const float*)d_in[20];
    const float* fwd_s = (const float*)d_in[21];
    const float* fwd_b = (const float*)d_in[22];
    const float* c1w = (const float*)d_in[23];
    const float* c1b = (const float*)d_in[24];
    const float* c2w = (const float*)d_in[25];
    const float* c2b = (const float*)d_in[26];
    const float* lls = (const float*)d_in[27];
    const float* llb = (const float*)d_in[28];

    const size_t RC = (size_t)NROW * HID;
    float* seqs = (float*)d_ws;
    float* Qn   = seqs + RC;
    float* qbuf = Qn   + RC;
    float* kbuf = qbuf + RC;
    float* vbuf = kbuf + RC;

    k_embed<<<NROW, 128, 0, stream>>>(logs, meta, iW, bW, cW, seqs);

    for (int i = 0; i < 2; ++i) {
        size_t wo = (size_t)i * HID * HID;
        size_t bo = (size_t)i * HID;
        k_lnqkv<<<NROW/8, 512, 0, stream>>>(seqs, attn_s + bo, attn_b + bo,
                                            Qw + wo, Qb + bo, Kw + wo, Kb + bo,
                                            Vw + wo, Vb + bo, posK, posV,
                                            Qn, qbuf, kbuf, vbuf);
        k_attn<<<NROW*NH, 64, 0, stream>>>(qbuf, (const float4*)kbuf,
                                           (const float4*)vbuf, (const float4*)Qn,
                                           (const float4*)tK, (const float4*)tV,
                                           tmat, logs, (float4*)seqs);
        k_ffn<<<NROW/8, 512, 0, stream>>>(seqs, fwd_s + bo, fwd_b + bo,
                                          c1w + wo, c1b + bo, c2w + wo, c2b + bo,
                                          logs, seqs);
    }

    k_logits<<<NROW, 128, 0, stream>>>(seqs, lls, llb, pos, neg, meta, iW, bW, cW, (float*)d_out);
}